// Round 5
// baseline (266.139 us; speedup 1.0000x reference)
//
#include <hip/hip_runtime.h>
#include <cstdint>
#include <cstddef>

#define D 256
#define E 256
#define T 128
#define QIN 640   // D + E + T
#define P 8
#define R 32      // batch rows per block
#define DP 260    // qpre row stride in floats

typedef __attribute__((ext_vector_type(8))) short bf16x8;
typedef __attribute__((ext_vector_type(4))) float f32x4;

__device__ __forceinline__ ushort f2bf(float f) {   // RNE fp32->bf16
  uint32_t u = __float_as_uint(f);
  u += 0x7fffu + ((u >> 16) & 1u);
  return (ushort)(u >> 16);
}

__device__ __forceinline__ bf16x8 cvt8(const float* p) {
  const float4 a = *(const float4*)p;
  const float4 b = *(const float4*)(p + 4);
  bf16x8 r;
  r[0] = (short)f2bf(a.x); r[1] = (short)f2bf(a.y);
  r[2] = (short)f2bf(a.z); r[3] = (short)f2bf(a.w);
  r[4] = (short)f2bf(b.x); r[5] = (short)f2bf(b.y);
  r[6] = (short)f2bf(b.z); r[7] = (short)f2bf(b.w);
  return r;
}

// 32-lane butterfly (offsets 16..1 stay within each 32-lane half)
__device__ __forceinline__ float wsum32(float v) {
#pragma unroll
  for (int o = 16; o > 0; o >>= 1) v += __shfl_xor(v, o, 64);
  return v;
}

__device__ __forceinline__ float clampf(float x, float lo, float hi) {
  return fminf(fmaxf(x, lo), hi);
}

// W2[((k>>3)*D + n)*8 + (k&7)] = bf16(Wq[n][k])
__global__ void prep_w2_kernel(const float* __restrict__ Wq, ushort* __restrict__ W2) {
  const int idx = blockIdx.x * 256 + threadIdx.x;
  const int n = idx / QIN;
  const int k = idx - n * QIN;
  W2[((((k >> 3) * D + n) << 3)) + (k & 7)] = f2bf(Wq[idx]);
}

template <bool PRE>
__global__ __launch_bounds__(256, 4) void fused_kernel(
    const float* __restrict__ raw, const float* __restrict__ edge,
    const float* __restrict__ tim, const float* __restrict__ proto,
    const float* __restrict__ Wq, const ushort* __restrict__ W2,
    const float* __restrict__ bq, const float* __restrict__ Wg,
    const float* __restrict__ bg, const float* __restrict__ temp,
    const float* __restrict__ lnw, const float* __restrict__ lnb,
    float* __restrict__ out) {
  __shared__ float qpre[R][DP];   // 33.3 KB

  const int tid = threadIdx.x;
  const int r0 = blockIdx.x * R;
  const int w = tid >> 6;
  const int lane = tid & 63;
  const int lr = lane & 15;   // A-row / C-col within tile
  const int lh = lane >> 4;   // k-group 0..3

  // ---- GEMM: A direct from global (fp32->bf16 in-register), B from W2 ----
  {
    f32x4 acc0[4], acc1[4];
#pragma unroll
    for (int c = 0; c < 4; ++c) {
      acc0[c] = (f32x4){0.f, 0.f, 0.f, 0.f};
      acc1[c] = (f32x4){0.f, 0.f, 0.f, 0.f};
    }
    const size_t gA0 = (size_t)(r0 + lr);
    const size_t gA1 = (size_t)(r0 + 16 + lr);

#pragma unroll
    for (int kb = 0; kb < QIN; kb += 32) {
      const float* s0;
      const float* s1;
      int o;
      if (kb < D)            { s0 = raw  + gA0 * D; s1 = raw  + gA1 * D; o = kb; }
      else if (kb < D + E)   { s0 = edge + gA0 * E; s1 = edge + gA1 * E; o = kb - D; }
      else                   { s0 = tim  + gA0 * T; s1 = tim  + gA1 * T; o = kb - D - E; }
      o += lh * 8;
      const bf16x8 a0 = cvt8(s0 + o);
      const bf16x8 a1 = cvt8(s1 + o);
#pragma unroll
      for (int c = 0; c < 4; ++c) {
        const int n = w * 64 + c * 16 + lr;
        bf16x8 bv;
        if (PRE) {
          bv = *(const bf16x8*)&W2[(((kb >> 3) + lh) * D + n) << 3];
        } else {
          bv = cvt8(Wq + (size_t)n * QIN + kb + lh * 8);
        }
        acc0[c] = __builtin_amdgcn_mfma_f32_16x16x32_bf16(a0, bv, acc0[c], 0, 0, 0);
        acc1[c] = __builtin_amdgcn_mfma_f32_16x16x32_bf16(a1, bv, acc1[c], 0, 0, 0);
      }
    }
    // C/D layout: col = lane&15, row = (lane>>4)*4 + reg
#pragma unroll
    for (int c = 0; c < 4; ++c) {
      const int n = w * 64 + c * 16 + lr;
      const float bqv = bq[n];
#pragma unroll
      for (int i = 0; i < 4; ++i) {
        qpre[lh * 4 + i][n]      = acc0[c][i] + bqv;
        qpre[16 + lh * 4 + i][n] = acc1[c][i] + bqv;
      }
    }
  }
  __syncthreads();

  // ---- epilogue: 2 rows per wave (32-lane groups); lane owns dims d0..d0+3, d1..d1+3 ----
  const int h = lane >> 5;
  const int l32 = lane & 31;
  const int d0 = l32 * 4;
  const int d1 = 128 + l32 * 4;

  const float4 lw0 = *(const float4*)(lnw + d0);
  const float4 lw1 = *(const float4*)(lnw + d1);
  const float4 lb0 = *(const float4*)(lnb + d0);
  const float4 lb1 = *(const float4*)(lnb + d1);
  const float4 wr0 = *(const float4*)(Wg + d0);
  const float4 wr1 = *(const float4*)(Wg + d1);
  const float4 wc0 = *(const float4*)(Wg + D + d0);
  const float4 wc1 = *(const float4*)(Wg + D + d1);
  const float4 wt  = *(const float4*)(Wg + 2 * D + l32 * 4);
  const float bgv = bg[0];
  const float invt = 1.0f / (clampf(temp[0], 0.5f, 5.0f) + 0.01f);

#pragma unroll 1
  for (int j = 0; j < 4; ++j) {
    const int r = j * 8 + w * 2 + h;
    const size_t g = (size_t)(r0 + r);
    const float* pb = proto + g * (size_t)(P * D);

    // issue gate inputs early (in flight through LN/sim)
    const float4 ra0 = *(const float4*)(raw + g * D + d0);
    const float4 ra1 = *(const float4*)(raw + g * D + d1);
    const float4 t4  = *(const float4*)(tim + g * T + l32 * 4);

    // LN + tanh -> q[8]
    const float4 x0 = *(const float4*)&qpre[r][d0];
    const float4 x1 = *(const float4*)&qpre[r][d1];
    float x[8] = {x0.x, x0.y, x0.z, x0.w, x1.x, x1.y, x1.z, x1.w};
    float s = 0.f;
#pragma unroll
    for (int i = 0; i < 8; ++i) s += x[i];
    const float mu = wsum32(s) * (1.0f / 256.0f);
    float v = 0.f;
#pragma unroll
    for (int i = 0; i < 8; ++i) { x[i] -= mu; v += x[i] * x[i]; }
    const float rstd = 1.0f / sqrtf(wsum32(v) * (1.0f / 256.0f) + 1e-6f);
    const float lwv[8] = {lw0.x, lw0.y, lw0.z, lw0.w, lw1.x, lw1.y, lw1.z, lw1.w};
    const float lbv[8] = {lb0.x, lb0.y, lb0.z, lb0.w, lb1.x, lb1.y, lb1.z, lb1.w};
    float q[8];
    float qs = 0.f;
#pragma unroll
    for (int i = 0; i < 8; ++i) {
      q[i] = tanhf(x[i] * rstd * lwv[i] + lbv[i]);
      qs += q[i] * q[i];
    }
    const float qdiv = fmaxf(sqrtf(wsum32(qs)), 1e-6f);

    // sim partials in 4-proto register chunks
    float dt[8], pn[8];
#pragma unroll
    for (int cch = 0; cch < 2; ++cch) {
      float4 A0[4], A1[4];
#pragma unroll
      for (int p = 0; p < 4; ++p) {
        A0[p] = *(const float4*)(pb + (size_t)(cch * 4 + p) * D + d0);
        A1[p] = *(const float4*)(pb + (size_t)(cch * 4 + p) * D + d1);
      }
#pragma unroll
      for (int p = 0; p < 4; ++p) {
        const int pi = cch * 4 + p;
        dt[pi] = q[0] * A0[p].x + q[1] * A0[p].y + q[2] * A0[p].z + q[3] * A0[p].w +
                 q[4] * A1[p].x + q[5] * A1[p].y + q[6] * A1[p].z + q[7] * A1[p].w;
        pn[pi] = A0[p].x * A0[p].x + A0[p].y * A0[p].y + A0[p].z * A0[p].z +
                 A0[p].w * A0[p].w + A1[p].x * A1[p].x + A1[p].y * A1[p].y +
                 A1[p].z * A1[p].z + A1[p].w * A1[p].w;
      }
    }
    // batched butterfly: 16 independent chains x 5 steps
#pragma unroll
    for (int o = 16; o > 0; o >>= 1) {
#pragma unroll
      for (int p = 0; p < P; ++p) {
        dt[p] += __shfl_xor(dt[p], o, 64);
        pn[p] += __shfl_xor(pn[p], o, 64);
      }
    }

    // issue cand chunk0 reloads (L1/L2-hot) before softmax math
    float4 C0[4], C1[4];
#pragma unroll
    for (int p = 0; p < 4; ++p) {
      C0[p] = *(const float4*)(pb + (size_t)p * D + d0);
      C1[p] = *(const float4*)(pb + (size_t)p * D + d1);
    }

    // softmax over P (redundant per lane)
    float sim[P];
#pragma unroll
    for (int p = 0; p < P; ++p) {
      const float pdiv = fmaxf(sqrtf(pn[p]), 1e-6f);
      sim[p] = clampf(dt[p] / (qdiv * pdiv), -10.0f, 10.0f) * invt;
    }
    float m = sim[0];
#pragma unroll
    for (int p = 1; p < P; ++p) m = fmaxf(m, sim[p]);
    float ssum = 0.f;
#pragma unroll
    for (int p = 0; p < P; ++p) { sim[p] = expf(sim[p] - m); ssum += sim[p]; }
    const float sinv = 1.0f / ssum;
#pragma unroll
    for (int p = 0; p < P; ++p) sim[p] = clampf(sim[p] * sinv, 0.0f, 1.0f);

    // candidate
    float cd[8] = {0.f, 0.f, 0.f, 0.f, 0.f, 0.f, 0.f, 0.f};
#pragma unroll
    for (int p = 0; p < 4; ++p) {
      cd[0] = fmaf(sim[p], C0[p].x, cd[0]); cd[1] = fmaf(sim[p], C0[p].y, cd[1]);
      cd[2] = fmaf(sim[p], C0[p].z, cd[2]); cd[3] = fmaf(sim[p], C0[p].w, cd[3]);
      cd[4] = fmaf(sim[p], C1[p].x, cd[4]); cd[5] = fmaf(sim[p], C1[p].y, cd[5]);
      cd[6] = fmaf(sim[p], C1[p].z, cd[6]); cd[7] = fmaf(sim[p], C1[p].w, cd[7]);
    }
#pragma unroll
    for (int p = 0; p < 4; ++p) {
      C0[p] = *(const float4*)(pb + (size_t)(4 + p) * D + d0);
      C1[p] = *(const float4*)(pb + (size_t)(4 + p) * D + d1);
    }
#pragma unroll
    for (int p = 0; p < 4; ++p) {
      const float a = sim[4 + p];
      cd[0] = fmaf(a, C0[p].x, cd[0]); cd[1] = fmaf(a, C0[p].y, cd[1]);
      cd[2] = fmaf(a, C0[p].z, cd[2]); cd[3] = fmaf(a, C0[p].w, cd[3]);
      cd[4] = fmaf(a, C1[p].x, cd[4]); cd[5] = fmaf(a, C1[p].y, cd[5]);
      cd[6] = fmaf(a, C1[p].z, cd[6]); cd[7] = fmaf(a, C1[p].w, cd[7]);
    }
#pragma unroll
    for (int i = 0; i < 8; ++i) cd[i] = clampf(cd[i], -5.0f, 5.0f);

    // gate
    const float rr[8] = {ra0.x, ra0.y, ra0.z, ra0.w, ra1.x, ra1.y, ra1.z, ra1.w};
    const float wrv[8] = {wr0.x, wr0.y, wr0.z, wr0.w, wr1.x, wr1.y, wr1.z, wr1.w};
    const float wcv[8] = {wc0.x, wc0.y, wc0.z, wc0.w, wc1.x, wc1.y, wc1.z, wc1.w};
    float gsum = clampf(t4.x, -50.f, 50.f) * wt.x + clampf(t4.y, -50.f, 50.f) * wt.y +
                 clampf(t4.z, -50.f, 50.f) * wt.z + clampf(t4.w, -50.f, 50.f) * wt.w;
#pragma unroll
    for (int i = 0; i < 8; ++i) {
      gsum += clampf(rr[i], -50.f, 50.f) * wrv[i];
      gsum += clampf(cd[i], -50.f, 50.f) * wcv[i];
    }
    const float z = clampf(wsum32(gsum) + bgv, -10.0f, 10.0f);
    const float gate = 1.0f / (1.0f + expf(-z));

    // gated update + final LN + clip
    float upd[8];
    float s2 = 0.f;
#pragma unroll
    for (int i = 0; i < 8; ++i) {
      upd[i] = (1.0f - gate) * rr[i] + gate * cd[i];
      s2 += upd[i];
    }
    const float mu2 = wsum32(s2) * (1.0f / 256.0f);
    float v2 = 0.f;
#pragma unroll
    for (int i = 0; i < 8; ++i) { upd[i] -= mu2; v2 += upd[i] * upd[i]; }
    const float rstd2 = 1.0f / sqrtf(wsum32(v2) * (1.0f / 256.0f) + 1e-6f);
    float4 y0, y1;
    y0.x = clampf(upd[0] * rstd2 * lwv[0] + lbv[0], -10.0f, 10.0f);
    y0.y = clampf(upd[1] * rstd2 * lwv[1] + lbv[1], -10.0f, 10.0f);
    y0.z = clampf(upd[2] * rstd2 * lwv[2] + lbv[2], -10.0f, 10.0f);
    y0.w = clampf(upd[3] * rstd2 * lwv[3] + lbv[3], -10.0f, 10.0f);
    y1.x = clampf(upd[4] * rstd2 * lwv[4] + lbv[4], -10.0f, 10.0f);
    y1.y = clampf(upd[5] * rstd2 * lwv[5] + lbv[5], -10.0f, 10.0f);
    y1.z = clampf(upd[6] * rstd2 * lwv[6] + lbv[6], -10.0f, 10.0f);
    y1.w = clampf(upd[7] * rstd2 * lwv[7] + lbv[7], -10.0f, 10.0f);
    *(float4*)(out + g * D + d0) = y0;
    *(float4*)(out + g * D + d1) = y1;
  }
}

extern "C" void kernel_launch(void* const* d_in, const int* in_sizes, int n_in,
                              void* d_out, int out_size, void* d_ws, size_t ws_size,
                              hipStream_t stream) {
  const float* raw   = (const float*)d_in[0];
  // d_in[1] = node_features: unused by the reference
  const float* edge  = (const float*)d_in[2];
  const float* tim   = (const float*)d_in[3];
  const float* proto = (const float*)d_in[4];
  const float* Wq    = (const float*)d_in[5];
  const float* bq    = (const float*)d_in[6];
  const float* Wg    = (const float*)d_in[7];
  const float* bg    = (const float*)d_in[8];
  const float* temp  = (const float*)d_in[9];
  const float* lnw   = (const float*)d_in[10];
  const float* lnb   = (const float*)d_in[11];
  float* out = (float*)d_out;

  const int B = in_sizes[0] / D;
  const int nblk = B / R;

  if (ws_size >= (size_t)QIN * D * sizeof(ushort)) {
    ushort* W2 = (ushort*)d_ws;
    prep_w2_kernel<<<(QIN * D) / 256, 256, 0, stream>>>(Wq, W2);
    fused_kernel<true><<<nblk, 256, 0, stream>>>(raw, edge, tim, proto, Wq, W2,
                                                 bq, Wg, bg, temp, lnw, lnb, out);
  } else {
    fused_kernel<false><<<nblk, 256, 0, stream>>>(raw, edge, tim, proto, Wq,
                                                  (const ushort*)nullptr, bq, Wg,
                                                  bg, temp, lnw, lnb, out);
  }
}